// Round 8
// baseline (327.670 us; speedup 1.0000x reference)
//
#include <hip/hip_runtime.h>
#include <stdint.h>

typedef float f32x4 __attribute__((ext_vector_type(4)));
typedef short s16x8 __attribute__((ext_vector_type(8)));

// N=16, C=256, H=32, W=32, K=4096, M = N*H*W = 16384
// d_out layout (floats): quant[4194304] | code[16384] | logit[67108864] | v[1048576]
#define QUANT_OFF 0
#define CODE_OFF  4194304
#define LOGIT_OFF 4210688
#define V_OFF     71319552

// logit std ~= 0.0625 (codebook prescaled by 1/sqrt(C)); bf16-path absmax err 0.00195.
// Margin must exceed 2*err (0.0039); use 1/128 for 2x headroom.
#define ARGMAX_MARGIN 0.0078125f

__device__ __forceinline__ unsigned short f2bf(float f) {
  unsigned int u = __float_as_uint(f);
  u = u + 0x7fffu + ((u >> 16) & 1u);   // RNE
  return (unsigned short)(u >> 16);
}

__device__ __forceinline__ void load_lds16(const void* g, void* l) {
  __builtin_amdgcn_global_load_lds(
      (const __attribute__((address_space(1))) unsigned int*)g,
      (__attribute__((address_space(3))) unsigned int*)l, 16, 0, 0);
}

// ---------------- K1a: k = cb@wk^T, v = cb@wv^T (fp32 VALU GEMM) ----------------
__global__ __launch_bounds__(256) void kv_kernel(
    const float* __restrict__ cb, const float* __restrict__ wk, const float* __restrict__ wv,
    float* __restrict__ kf, unsigned short* __restrict__ kh, float* __restrict__ vout)
{
  __shared__ __align__(16) float Xs[64][260];
  const int t = threadIdx.x;
  const int rowBase = blockIdx.x * 64;
  const int colBase = blockIdx.y * 64;
  const f32x4* cb4 = (const f32x4*)cb;
  #pragma unroll
  for (int it = 0; it < 16; ++it) {
    int chunk = it * 256 + t;
    int row = chunk >> 6, kq = chunk & 63;
    f32x4 vv = cb4[(rowBase + row) * 64 + kq];
    *(f32x4*)&Xs[row][kq * 4] = vv;
  }
  __syncthreads();
  const int tx = t & 15, ty = t >> 4;
  const int c0 = colBase + tx * 4;
  float accK[4][4] = {{0.f}}, accV[4][4] = {{0.f}};
  const f32x4* wk4 = (const f32x4*)wk;
  const f32x4* wv4 = (const f32x4*)wv;
  #pragma unroll 2
  for (int kc = 0; kc < 64; ++kc) {
    f32x4 a[4];
    #pragma unroll
    for (int i = 0; i < 4; ++i) a[i] = *(const f32x4*)&Xs[ty * 4 + i][kc * 4];
    #pragma unroll
    for (int j = 0; j < 4; ++j) {
      f32x4 bk = wk4[(c0 + j) * 64 + kc];
      f32x4 bv = wv4[(c0 + j) * 64 + kc];
      #pragma unroll
      for (int i = 0; i < 4; ++i) {
        accK[i][j] = fmaf(a[i].x, bk.x, accK[i][j]);
        accK[i][j] = fmaf(a[i].y, bk.y, accK[i][j]);
        accK[i][j] = fmaf(a[i].z, bk.z, accK[i][j]);
        accK[i][j] = fmaf(a[i].w, bk.w, accK[i][j]);
        accV[i][j] = fmaf(a[i].x, bv.x, accV[i][j]);
        accV[i][j] = fmaf(a[i].y, bv.y, accV[i][j]);
        accV[i][j] = fmaf(a[i].z, bv.z, accV[i][j]);
        accV[i][j] = fmaf(a[i].w, bv.w, accV[i][j]);
      }
    }
  }
  #pragma unroll
  for (int i = 0; i < 4; ++i) {
    int r = rowBase + ty * 4 + i;
    f32x4 vk = {accK[i][0], accK[i][1], accK[i][2], accK[i][3]};
    f32x4 vv = {accV[i][0], accV[i][1], accV[i][2], accV[i][3]};
    *(f32x4*)&kf[r * 256 + c0] = vk;
    *(f32x4*)&vout[r * 256 + c0] = vv;
    ushort4 hk;
    hk.x = f2bf(accK[i][0]); hk.y = f2bf(accK[i][1]);
    hk.z = f2bf(accK[i][2]); hk.w = f2bf(accK[i][3]);
    *(ushort4*)&kh[r * 256 + c0] = hk;
  }
}

// ---------------- K1b: q = x@wq^T (fp32 VALU GEMM), qh = bf16(q/16) ----------------
__global__ __launch_bounds__(256) void q_kernel(
    const float* __restrict__ latent, const float* __restrict__ wq,
    float* __restrict__ qf, unsigned short* __restrict__ qh)
{
  __shared__ __align__(16) float Xs[64][260];
  const int t = threadIdx.x;
  const int rowBase = blockIdx.x * 64;
  const int n = rowBase >> 10;
  const int hw0 = rowBase & 1023;
  const int colBase = blockIdx.y * 64;
  const f32x4* lat4 = (const f32x4*)latent;
  #pragma unroll
  for (int it = 0; it < 16; ++it) {
    int chunk = it * 256 + t;
    int k = chunk >> 4, rq = chunk & 15;
    f32x4 vv = lat4[(n * 256 + k) * 256 + (hw0 >> 2) + rq];
    Xs[rq * 4 + 0][k] = vv.x;
    Xs[rq * 4 + 1][k] = vv.y;
    Xs[rq * 4 + 2][k] = vv.z;
    Xs[rq * 4 + 3][k] = vv.w;
  }
  __syncthreads();
  const int tx = t & 15, ty = t >> 4;
  const int c0 = colBase + tx * 4;
  float acc[4][4] = {{0.f}};
  const f32x4* wq4 = (const f32x4*)wq;
  #pragma unroll 2
  for (int kc = 0; kc < 64; ++kc) {
    f32x4 a[4];
    #pragma unroll
    for (int i = 0; i < 4; ++i) a[i] = *(const f32x4*)&Xs[ty * 4 + i][kc * 4];
    #pragma unroll
    for (int j = 0; j < 4; ++j) {
      f32x4 b = wq4[(c0 + j) * 64 + kc];
      #pragma unroll
      for (int i = 0; i < 4; ++i) {
        acc[i][j] = fmaf(a[i].x, b.x, acc[i][j]);
        acc[i][j] = fmaf(a[i].y, b.y, acc[i][j]);
        acc[i][j] = fmaf(a[i].z, b.z, acc[i][j]);
        acc[i][j] = fmaf(a[i].w, b.w, acc[i][j]);
      }
    }
  }
  #pragma unroll
  for (int i = 0; i < 4; ++i) {
    int r = rowBase + ty * 4 + i;
    f32x4 vq = {acc[i][0], acc[i][1], acc[i][2], acc[i][3]};
    *(f32x4*)&qf[r * 256 + c0] = vq;
    ushort4 hq;
    hq.x = f2bf(acc[i][0] * 0.0625f); hq.y = f2bf(acc[i][1] * 0.0625f);
    hq.z = f2bf(acc[i][2] * 0.0625f); hq.w = f2bf(acc[i][3] * 0.0625f);
    *(ushort4*)&qh[r * 256 + c0] = hq;
  }
}

// ---------------- K2: logit = qh @ kh^T (bf16 MFMA) + fused per-(row,128col) blockmax ----------------
__global__ __launch_bounds__(256) void logit_gemm(
    const unsigned short* __restrict__ qh, const unsigned short* __restrict__ kh,
    float* __restrict__ out, float* __restrict__ pmax)
{
  __shared__ short As[128 * 64];
  __shared__ short Bs[128 * 64];
  __shared__ float Pm[128][2];
  const int t = threadIdx.x;
  const int bid = blockIdx.x;
  const int wg = (bid & 7) * 512 + (bid >> 3);  // XCD-chunked swizzle (4096 % 8 == 0)
  const int aRow0 = (wg >> 5) * 128;            // M block
  const int bRow0 = (wg & 31) * 128;            // N block
  const int lane = t & 63, wid = t >> 6;
  const int wr = wid >> 1, wc = wid & 1;
  f32x4 acc[4][4];
  #pragma unroll
  for (int m = 0; m < 4; ++m)
    #pragma unroll
    for (int n = 0; n < 4; ++n) { acc[m][n].x = 0.f; acc[m][n].y = 0.f; acc[m][n].z = 0.f; acc[m][n].w = 0.f; }

  const short* qs = (const short*)qh;
  const short* ks = (const short*)kh;
  for (int kt = 0; kt < 4; ++kt) {
    __syncthreads();
    #pragma unroll
    for (int ci = 0; ci < 4; ++ci) {
      int c = ci * 256 + t;
      int row = c >> 3;
      int slot = (c & 7) ^ (row & 7);           // inverse swizzle on SOURCE, linear dest
      int koff = kt * 64 + slot * 8;
      load_lds16(qs + (size_t)(aRow0 + row) * 256 + koff, As + c * 8);
      load_lds16(ks + (size_t)(bRow0 + row) * 256 + koff, Bs + c * 8);
    }
    __syncthreads();
    #pragma unroll
    for (int kstep = 0; kstep < 2; ++kstep) {
      s16x8 af[4], bfr[4];
      #pragma unroll
      for (int m = 0; m < 4; ++m) {
        int row = wr * 64 + m * 16 + (lane & 15);
        int slot = (kstep * 4 + (lane >> 4)) ^ (row & 7);
        af[m] = *(const s16x8*)(As + row * 64 + slot * 8);
      }
      #pragma unroll
      for (int n = 0; n < 4; ++n) {
        int row = wc * 64 + n * 16 + (lane & 15);
        int slot = (kstep * 4 + (lane >> 4)) ^ (row & 7);
        bfr[n] = *(const s16x8*)(Bs + row * 64 + slot * 8);
      }
      #pragma unroll
      for (int m = 0; m < 4; ++m)
        #pragma unroll
        for (int n = 0; n < 4; ++n)
          acc[m][n] = __builtin_amdgcn_mfma_f32_16x16x32_bf16(af[m], bfr[n], acc[m][n], 0, 0, 0);
    }
  }
  // fused blockmax: per (row, this 128-col block) max, into Pm then pmax
  #pragma unroll
  for (int m = 0; m < 4; ++m)
    #pragma unroll
    for (int j = 0; j < 4; ++j) {
      float bm = fmaxf(fmaxf(acc[m][0][j], acc[m][1][j]),
                       fmaxf(acc[m][2][j], acc[m][3][j]));
      #pragma unroll
      for (int off = 1; off < 16; off <<= 1) bm = fmaxf(bm, __shfl_xor(bm, off));
      if ((lane & 15) == 0) Pm[wr * 64 + m * 16 + (lane >> 4) * 4 + j][wc] = bm;
    }
  // logit store
  const int colLane = lane & 15, rowQuad = (lane >> 4) * 4;
  #pragma unroll
  for (int m = 0; m < 4; ++m)
    #pragma unroll
    for (int n = 0; n < 4; ++n) {
      int row = aRow0 + wr * 64 + m * 16 + rowQuad;
      int col = bRow0 + wc * 64 + n * 16 + colLane;
      #pragma unroll
      for (int j = 0; j < 4; ++j)
        out[(size_t)(row + j) * 4096 + col] = acc[m][n][j];
    }
  __syncthreads();
  if (t < 128) pmax[(size_t)(aRow0 + t) * 32 + (bRow0 >> 7)] = fmaxf(Pm[t][0], Pm[t][1]);
}

// ---------------- K3: finalize — gmax from pmax, rescan candidate block(s), exact recheck, gather ----------------
// 1024 threads: 16 waves x 2 rows, then cooperative transpose-gather.
__global__ __launch_bounds__(1024) void finalize_kernel(
    const float* __restrict__ logit, const float* __restrict__ pmax,
    const float* __restrict__ qf, const float* __restrict__ kf,
    const float* __restrict__ vout, float* __restrict__ quant, float* __restrict__ code)
{
  __shared__ __align__(16) float Vs[32][260];
  __shared__ int idxArr[32];
  const int t = threadIdx.x, wave = t >> 6, lane = t & 63;
  const int nh = blockIdx.x, n = nh >> 5, h = nh & 31;
  #pragma unroll 1
  for (int ri = 0; ri < 2; ++ri) {
    const int w = wave * 2 + ri;
    const size_t r = (size_t)nh * 32 + w;
    float pv = -3e38f;
    if (lane < 32) pv = pmax[r * 32 + lane];
    float gmax = pv;
    #pragma unroll
    for (int off = 32; off; off >>= 1) gmax = fmaxf(gmax, __shfl_xor(gmax, off));
    const float thr = gmax - ARGMAX_MARGIN;
    unsigned long long bm = __ballot(pv >= thr); // candidate 128-col blocks (usually 1)
    const f32x4 qv = ((const f32x4*)(qf + r * 256))[lane];
    float bestV = -3e38f; int bestJ = 0x7fffffff;
    #pragma unroll 1
    while (bm) {
      const int nb = __ffsll(bm) - 1; bm &= bm - 1;
      const float2 lv = *(const float2*)&logit[r * 4096 + nb * 128 + lane * 2];
      unsigned long long c0 = __ballot(lv.x >= thr);
      unsigned long long c1 = __ballot(lv.y >= thr);
      #pragma unroll 1
      for (int half = 0; half < 2; ++half) {
        unsigned long long mm = half ? c1 : c0;
        #pragma unroll 1
        while (mm) {
          const int L = __ffsll(mm) - 1; mm &= mm - 1;
          const int j = nb * 128 + L * 2 + half;
          const f32x4 kv = ((const f32x4*)(kf + (size_t)j * 256))[lane];
          double s = (double)qv.x * kv.x + (double)qv.y * kv.y
                   + (double)qv.z * kv.z + (double)qv.w * kv.w;
          #pragma unroll
          for (int off = 32; off; off >>= 1) s += __shfl_xor(s, off);
          const float val = (float)(s * 0.0625);
          if (val > bestV || (val == bestV && j < bestJ)) { bestV = val; bestJ = j; }
        }
      }
    }
    if (lane == 0) idxArr[w] = bestJ;
  }
  __syncthreads();
  // stage the 32 selected v-rows in LDS (coalesced reads)
  #pragma unroll 1
  for (int ri = 0; ri < 2; ++ri) {
    const int w2 = wave * 2 + ri;
    const int idx = idxArr[w2];
    const f32x4 vv = ((const f32x4*)(vout + (size_t)idx * 256))[lane];
    *(f32x4*)&Vs[w2][lane * 4] = vv;
  }
  __syncthreads();
  // transposed write: quant[n][c][h][w], w contiguous
  const int wcol = t & 31, cg = t >> 5;
  #pragma unroll
  for (int cc = 0; cc < 8; ++cc) {
    const int c = cg * 8 + cc;
    quant[(((size_t)n * 256 + c) * 32 + h) * 32 + wcol] = Vs[wcol][c];
  }
  if (t < 32) code[nh * 32 + t] = (float)(idxArr[t] & 255);
}

extern "C" void kernel_launch(void* const* d_in, const int* in_sizes, int n_in,
                              void* d_out, int out_size, void* d_ws, size_t ws_size,
                              hipStream_t stream) {
  (void)in_sizes; (void)n_in; (void)out_size; (void)ws_size;
  const float* latent = (const float*)d_in[0];
  const float* cb     = (const float*)d_in[1];
  const float* wq     = (const float*)d_in[2];
  const float* wk     = (const float*)d_in[3];
  const float* wv     = (const float*)d_in[4];

  float* out   = (float*)d_out;
  float* quant = out + QUANT_OFF;
  float* code  = out + CODE_OFF;
  float* logit = out + LOGIT_OFF;
  float* vout  = out + V_OFF;

  char* ws = (char*)d_ws;
  float*          qf   = (float*)(ws + 0);                 // 16 MB
  float*          kf   = (float*)(ws + 16777216);          // 4 MB
  unsigned short* qh   = (unsigned short*)(ws + 20971520); // 8 MB
  unsigned short* kh   = (unsigned short*)(ws + 29360128); // 2 MB
  float*          pmax = (float*)(ws + 31457280);          // 2 MB (16384 x 32)

  kv_kernel<<<dim3(64, 4), 256, 0, stream>>>(cb, wk, wv, kf, kh, vout);
  q_kernel<<<dim3(256, 4), 256, 0, stream>>>(latent, wq, qf, qh);
  logit_gemm<<<4096, 256, 0, stream>>>(qh, kh, logit, pmax);
  finalize_kernel<<<512, 1024, 0, stream>>>(logit, pmax, qf, kf, vout, quant, code);
}

// Round 10
// 298.767 us; speedup vs baseline: 1.0967x; 1.0967x over previous
//
#include <hip/hip_runtime.h>
#include <stdint.h>

typedef float f32x4 __attribute__((ext_vector_type(4)));
typedef short s16x8 __attribute__((ext_vector_type(8)));

// N=16, C=256, H=32, W=32, K=4096, M = N*H*W = 16384
// d_out layout (floats): quant[4194304] | code[16384] | logit[67108864] | v[1048576]
#define QUANT_OFF 0
#define CODE_OFF  4194304
#define LOGIT_OFF 4210688
#define V_OFF     71319552

// logit std ~= 0.0625 (codebook prescaled by 1/sqrt(C)); bf16-path absmax err 0.00195.
// Margin must exceed 2*err (0.0039); use 1/128 for 2x headroom.
#define ARGMAX_MARGIN 0.0078125f

__device__ __forceinline__ unsigned short f2bf(float f) {
  unsigned int u = __float_as_uint(f);
  u = u + 0x7fffu + ((u >> 16) & 1u);   // RNE
  return (unsigned short)(u >> 16);
}

__device__ __forceinline__ void load_lds16(const void* g, void* l) {
  __builtin_amdgcn_global_load_lds(
      (const __attribute__((address_space(1))) unsigned int*)g,
      (__attribute__((address_space(3))) unsigned int*)l, 16, 0, 0);
}

// ---------------- K1a: k = cb@wk^T, v = cb@wv^T (fp32 VALU GEMM) ----------------
__global__ __launch_bounds__(256) void kv_kernel(
    const float* __restrict__ cb, const float* __restrict__ wk, const float* __restrict__ wv,
    float* __restrict__ kf, unsigned short* __restrict__ kh, float* __restrict__ vout)
{
  __shared__ __align__(16) float Xs[64][260];
  const int t = threadIdx.x;
  const int rowBase = blockIdx.x * 64;
  const int colBase = blockIdx.y * 64;
  const f32x4* cb4 = (const f32x4*)cb;
  #pragma unroll
  for (int it = 0; it < 16; ++it) {
    int chunk = it * 256 + t;
    int row = chunk >> 6, kq = chunk & 63;
    f32x4 vv = cb4[(rowBase + row) * 64 + kq];
    *(f32x4*)&Xs[row][kq * 4] = vv;
  }
  __syncthreads();
  const int tx = t & 15, ty = t >> 4;
  const int c0 = colBase + tx * 4;
  float accK[4][4] = {{0.f}}, accV[4][4] = {{0.f}};
  const f32x4* wk4 = (const f32x4*)wk;
  const f32x4* wv4 = (const f32x4*)wv;
  #pragma unroll 2
  for (int kc = 0; kc < 64; ++kc) {
    f32x4 a[4];
    #pragma unroll
    for (int i = 0; i < 4; ++i) a[i] = *(const f32x4*)&Xs[ty * 4 + i][kc * 4];
    #pragma unroll
    for (int j = 0; j < 4; ++j) {
      f32x4 bk = wk4[(c0 + j) * 64 + kc];
      f32x4 bv = wv4[(c0 + j) * 64 + kc];
      #pragma unroll
      for (int i = 0; i < 4; ++i) {
        accK[i][j] = fmaf(a[i].x, bk.x, accK[i][j]);
        accK[i][j] = fmaf(a[i].y, bk.y, accK[i][j]);
        accK[i][j] = fmaf(a[i].z, bk.z, accK[i][j]);
        accK[i][j] = fmaf(a[i].w, bk.w, accK[i][j]);
        accV[i][j] = fmaf(a[i].x, bv.x, accV[i][j]);
        accV[i][j] = fmaf(a[i].y, bv.y, accV[i][j]);
        accV[i][j] = fmaf(a[i].z, bv.z, accV[i][j]);
        accV[i][j] = fmaf(a[i].w, bv.w, accV[i][j]);
      }
    }
  }
  #pragma unroll
  for (int i = 0; i < 4; ++i) {
    int r = rowBase + ty * 4 + i;
    f32x4 vk = {accK[i][0], accK[i][1], accK[i][2], accK[i][3]};
    f32x4 vv = {accV[i][0], accV[i][1], accV[i][2], accV[i][3]};
    *(f32x4*)&kf[r * 256 + c0] = vk;
    *(f32x4*)&vout[r * 256 + c0] = vv;
    ushort4 hk;
    hk.x = f2bf(accK[i][0]); hk.y = f2bf(accK[i][1]);
    hk.z = f2bf(accK[i][2]); hk.w = f2bf(accK[i][3]);
    *(ushort4*)&kh[r * 256 + c0] = hk;
  }
}

// ---------------- K1b: q = x@wq^T (fp32 VALU GEMM), qh = bf16(q/16) ----------------
__global__ __launch_bounds__(256) void q_kernel(
    const float* __restrict__ latent, const float* __restrict__ wq,
    float* __restrict__ qf, unsigned short* __restrict__ qh)
{
  __shared__ __align__(16) float Xs[64][260];
  const int t = threadIdx.x;
  const int rowBase = blockIdx.x * 64;
  const int n = rowBase >> 10;
  const int hw0 = rowBase & 1023;
  const int colBase = blockIdx.y * 64;
  const f32x4* lat4 = (const f32x4*)latent;
  #pragma unroll
  for (int it = 0; it < 16; ++it) {
    int chunk = it * 256 + t;
    int k = chunk >> 4, rq = chunk & 15;
    f32x4 vv = lat4[(n * 256 + k) * 256 + (hw0 >> 2) + rq];
    Xs[rq * 4 + 0][k] = vv.x;
    Xs[rq * 4 + 1][k] = vv.y;
    Xs[rq * 4 + 2][k] = vv.z;
    Xs[rq * 4 + 3][k] = vv.w;
  }
  __syncthreads();
  const int tx = t & 15, ty = t >> 4;
  const int c0 = colBase + tx * 4;
  float acc[4][4] = {{0.f}};
  const f32x4* wq4 = (const f32x4*)wq;
  #pragma unroll 2
  for (int kc = 0; kc < 64; ++kc) {
    f32x4 a[4];
    #pragma unroll
    for (int i = 0; i < 4; ++i) a[i] = *(const f32x4*)&Xs[ty * 4 + i][kc * 4];
    #pragma unroll
    for (int j = 0; j < 4; ++j) {
      f32x4 b = wq4[(c0 + j) * 64 + kc];
      #pragma unroll
      for (int i = 0; i < 4; ++i) {
        acc[i][j] = fmaf(a[i].x, b.x, acc[i][j]);
        acc[i][j] = fmaf(a[i].y, b.y, acc[i][j]);
        acc[i][j] = fmaf(a[i].z, b.z, acc[i][j]);
        acc[i][j] = fmaf(a[i].w, b.w, acc[i][j]);
      }
    }
  }
  #pragma unroll
  for (int i = 0; i < 4; ++i) {
    int r = rowBase + ty * 4 + i;
    f32x4 vq = {acc[i][0], acc[i][1], acc[i][2], acc[i][3]};
    *(f32x4*)&qf[r * 256 + c0] = vq;
    ushort4 hq;
    hq.x = f2bf(acc[i][0] * 0.0625f); hq.y = f2bf(acc[i][1] * 0.0625f);
    hq.z = f2bf(acc[i][2] * 0.0625f); hq.w = f2bf(acc[i][3] * 0.0625f);
    *(ushort4*)&qh[r * 256 + c0] = hq;
  }
}

// ---------------- K2: logit = qh @ kh^T (bf16 MFMA) + fused blockmax ----------------
// BK=32 double-buffered staging, ONE __syncthreads per K-step: prefetch of tile
// kt+1 issues after the barrier and flies under tile kt's 16 MFMAs. Scalar logit
// store epilogue kept verbatim from the proven round-3 kernel.
__global__ __launch_bounds__(256) void logit_gemm(
    const unsigned short* __restrict__ qh, const unsigned short* __restrict__ kh,
    float* __restrict__ out, float* __restrict__ pmax)
{
  __shared__ short AsBuf[2][128 * 32];
  __shared__ short BsBuf[2][128 * 32];
  __shared__ float Pm[128][2];
  const int t = threadIdx.x;
  const int bid = blockIdx.x;
  const int wg = (bid & 7) * 512 + (bid >> 3);  // XCD-chunked swizzle (4096 % 8 == 0)
  const int aRow0 = (wg >> 5) * 128;            // M block
  const int bRow0 = (wg & 31) * 128;            // N block
  const int lane = t & 63, wid = t >> 6;
  const int wr = wid >> 1, wc = wid & 1;
  f32x4 acc[4][4];
  #pragma unroll
  for (int m = 0; m < 4; ++m)
    #pragma unroll
    for (int n = 0; n < 4; ++n) { acc[m][n].x = 0.f; acc[m][n].y = 0.f; acc[m][n].z = 0.f; acc[m][n].w = 0.f; }

  const short* qs = (const short*)qh;
  const short* ks = (const short*)kh;

  // 128x32 bf16 tile = 512 x 16B chunks per matrix; 2 chunks/thread each.
  // LDS linear dest (chunk c -> row=c>>2, slot=c&3); XOR swizzle on SOURCE koff.
  #define STAGE32(AB, BB, KT) do {                                          \
    _Pragma("unroll")                                                       \
    for (int ci = 0; ci < 2; ++ci) {                                        \
      int c = ci * 256 + t;                                                 \
      int row = c >> 2;                                                     \
      int slot = (c & 3) ^ (row & 3);                                       \
      int koff = (KT) * 32 + slot * 8;                                      \
      load_lds16(qs + (size_t)(aRow0 + row) * 256 + koff, (AB) + c * 8);    \
      load_lds16(ks + (size_t)(bRow0 + row) * 256 + koff, (BB) + c * 8);    \
    } } while (0)

  STAGE32(AsBuf[0], BsBuf[0], 0);
  #pragma unroll
  for (int kt = 0; kt < 8; ++kt) {
    const int buf = kt & 1;
    __syncthreads();                       // drains buf's loads; fences prev reads of buf^1
    if (kt < 7) STAGE32(AsBuf[buf ^ 1], BsBuf[buf ^ 1], kt + 1);
    const short* As = AsBuf[buf];
    const short* Bs = BsBuf[buf];
    s16x8 af[4], bfr[4];
    #pragma unroll
    for (int m = 0; m < 4; ++m) {
      int row = wr * 64 + m * 16 + (lane & 15);
      int slot = (lane >> 4) ^ (row & 3);
      af[m] = *(const s16x8*)(As + row * 32 + slot * 8);
    }
    #pragma unroll
    for (int n = 0; n < 4; ++n) {
      int row = wc * 64 + n * 16 + (lane & 15);
      int slot = (lane >> 4) ^ (row & 3);
      bfr[n] = *(const s16x8*)(Bs + row * 32 + slot * 8);
    }
    #pragma unroll
    for (int m = 0; m < 4; ++m)
      #pragma unroll
      for (int n = 0; n < 4; ++n)
        acc[m][n] = __builtin_amdgcn_mfma_f32_16x16x32_bf16(af[m], bfr[n], acc[m][n], 0, 0, 0);
  }
  #undef STAGE32

  // fused blockmax: per (row, this 128-col block) max, into Pm then pmax
  #pragma unroll
  for (int m = 0; m < 4; ++m)
    #pragma unroll
    for (int j = 0; j < 4; ++j) {
      float bm = fmaxf(fmaxf(acc[m][0][j], acc[m][1][j]),
                       fmaxf(acc[m][2][j], acc[m][3][j]));
      #pragma unroll
      for (int off = 1; off < 16; off <<= 1) bm = fmaxf(bm, __shfl_xor(bm, off));
      if ((lane & 15) == 0) Pm[wr * 64 + m * 16 + (lane >> 4) * 4 + j][wc] = bm;
    }
  // logit store (proven scalar epilogue — L2 merges the 64B segments)
  const int colLane = lane & 15, rowQuad = (lane >> 4) * 4;
  #pragma unroll
  for (int m = 0; m < 4; ++m)
    #pragma unroll
    for (int n = 0; n < 4; ++n) {
      int row = aRow0 + wr * 64 + m * 16 + rowQuad;
      int col = bRow0 + wc * 64 + n * 16 + colLane;
      #pragma unroll
      for (int j = 0; j < 4; ++j)
        out[(size_t)(row + j) * 4096 + col] = acc[m][n][j];
    }
  __syncthreads();
  if (t < 128) pmax[(size_t)(aRow0 + t) * 32 + (bRow0 >> 7)] = fmaxf(Pm[t][0], Pm[t][1]);
}

// ---------------- K3: finalize — gmax from pmax, rescan candidate block(s), exact recheck, gather ----------------
// 1024 threads: 16 waves x 2 rows (ri loop now compiler-interleavable), then transpose-gather.
__global__ __launch_bounds__(1024) void finalize_kernel(
    const float* __restrict__ logit, const float* __restrict__ pmax,
    const float* __restrict__ qf, const float* __restrict__ kf,
    const float* __restrict__ vout, float* __restrict__ quant, float* __restrict__ code)
{
  __shared__ __align__(16) float Vs[32][260];
  __shared__ int idxArr[32];
  const int t = threadIdx.x, wave = t >> 6, lane = t & 63;
  const int nh = blockIdx.x, n = nh >> 5, h = nh & 31;
  for (int ri = 0; ri < 2; ++ri) {
    const int w = wave * 2 + ri;
    const size_t r = (size_t)nh * 32 + w;
    float pv = -3e38f;
    if (lane < 32) pv = pmax[r * 32 + lane];
    float gmax = pv;
    #pragma unroll
    for (int off = 32; off; off >>= 1) gmax = fmaxf(gmax, __shfl_xor(gmax, off));
    const float thr = gmax - ARGMAX_MARGIN;
    unsigned long long bm = __ballot(pv >= thr); // candidate 128-col blocks (usually 1)
    const f32x4 qv = ((const f32x4*)(qf + r * 256))[lane];
    float bestV = -3e38f; int bestJ = 0x7fffffff;
    #pragma unroll 1
    while (bm) {
      const int nb = __ffsll(bm) - 1; bm &= bm - 1;
      const float2 lv = *(const float2*)&logit[r * 4096 + nb * 128 + lane * 2];
      unsigned long long c0 = __ballot(lv.x >= thr);
      unsigned long long c1 = __ballot(lv.y >= thr);
      #pragma unroll 1
      for (int half = 0; half < 2; ++half) {
        unsigned long long mm = half ? c1 : c0;
        #pragma unroll 1
        while (mm) {
          const int L = __ffsll(mm) - 1; mm &= mm - 1;
          const int j = nb * 128 + L * 2 + half;
          const f32x4 kv = ((const f32x4*)(kf + (size_t)j * 256))[lane];
          double s = (double)qv.x * kv.x + (double)qv.y * kv.y
                   + (double)qv.z * kv.z + (double)qv.w * kv.w;
          #pragma unroll
          for (int off = 32; off; off >>= 1) s += __shfl_xor(s, off);
          const float val = (float)(s * 0.0625);
          if (val > bestV || (val == bestV && j < bestJ)) { bestV = val; bestJ = j; }
        }
      }
    }
    if (lane == 0) idxArr[w] = bestJ;
  }
  __syncthreads();
  // stage the 32 selected v-rows in LDS (coalesced reads)
  for (int ri = 0; ri < 2; ++ri) {
    const int w2 = wave * 2 + ri;
    const int idx = idxArr[w2];
    const f32x4 vv = ((const f32x4*)(vout + (size_t)idx * 256))[lane];
    *(f32x4*)&Vs[w2][lane * 4] = vv;
  }
  __syncthreads();
  // transposed write: quant[n][c][h][w], w contiguous
  const int wcol = t & 31, cg = t >> 5;
  #pragma unroll
  for (int cc = 0; cc < 8; ++cc) {
    const int c = cg * 8 + cc;
    quant[(((size_t)n * 256 + c) * 32 + h) * 32 + wcol] = Vs[wcol][c];
  }
  if (t < 32) code[nh * 32 + t] = (float)(idxArr[t] & 255);
}

extern "C" void kernel_launch(void* const* d_in, const int* in_sizes, int n_in,
                              void* d_out, int out_size, void* d_ws, size_t ws_size,
                              hipStream_t stream) {
  (void)in_sizes; (void)n_in; (void)out_size; (void)ws_size;
  const float* latent = (const float*)d_in[0];
  const float* cb     = (const float*)d_in[1];
  const float* wq     = (const float*)d_in[2];
  const float* wk     = (const float*)d_in[3];
  const float* wv     = (const float*)d_in[4];

  float* out   = (float*)d_out;
  float* quant = out + QUANT_OFF;
  float* code  = out + CODE_OFF;
  float* logit = out + LOGIT_OFF;
  float* vout  = out + V_OFF;

  char* ws = (char*)d_ws;
  float*          qf   = (float*)(ws + 0);                 // 16 MB
  float*          kf   = (float*)(ws + 16777216);          // 4 MB
  unsigned short* qh   = (unsigned short*)(ws + 20971520); // 8 MB
  unsigned short* kh   = (unsigned short*)(ws + 29360128); // 2 MB
  float*          pmax = (float*)(ws + 31457280);          // 2 MB (16384 x 32)

  kv_kernel<<<dim3(64, 4), 256, 0, stream>>>(cb, wk, wv, kf, kh, vout);
  q_kernel<<<dim3(256, 4), 256, 0, stream>>>(latent, wq, qf, qh);
  logit_gemm<<<4096, 256, 0, stream>>>(qh, kh, logit, pmax);
  finalize_kernel<<<512, 1024, 0, stream>>>(logit, pmax, qf, kf, vout, quant, code);
}